// Round 3
// baseline (485.005 us; speedup 1.0000x reference)
//
#include <hip/hip_runtime.h>

// ---------------------------------------------------------------------------
// Attention_73813307949177
//   kx = k Wk^T + bk ; qx = q Wq^T + bq
//   score = softmax2(softmax1(qx kx^T + bias)*wei + bias)
//   out = score (kx Wp^T) + bp   [associativity, validated R9]
// Outputs (concat): out [4096,1024] fp32, score [4096,4096] fp32
//
// R12 -> R13: COUNTED VMCNT (T4). R12 proved SQ_LDS_BANK_CONFLICT = exactly
// 4 per ds_read_b128 under ANY seg swizzle (structural: 64B rows + 16B
// granule reach only 8 bank-slots for 32 lanes) -> conflicts are priced in,
// not fixable. Real residual: ~800cy/phase dead time from vmcnt(0) full
// drain each tile (2 buffers = prefetch distance 1). New score loop:
// BK=16, FOUR 32KB LDS buffers (same 128KB), prefetch distance 3, ONE
// barrier per tile, constant vmcnt(8) in main loop (never 0 till epilogue).
// Single barrier/tile lets waves drift -> LDS reads overlap MFMA across
// waves (T5 setprio now has role-split). Accumulation order bit-identical.
// ---------------------------------------------------------------------------

typedef __bf16 bf16;
typedef __bf16 bf16x8 __attribute__((ext_vector_type(8)));
typedef __bf16 bf16x4 __attribute__((ext_vector_type(4)));
typedef float  f32x4  __attribute__((ext_vector_type(4)));
typedef float  f32x16 __attribute__((ext_vector_type(16)));
typedef int    i32x4  __attribute__((ext_vector_type(4)));

typedef __attribute__((address_space(1))) void as1_void;
typedef __attribute__((address_space(3))) void as3_void;

#define NQ  4096
#define NKK 4096
#define EMB 1024

#define BM 128
#define BN 128
#define BK 32

__device__ __forceinline__ void gld_lds16(const void* g, void* l) {
    __builtin_amdgcn_global_load_lds((as1_void*)g, (as3_void*)l, 16, 0, 0);
}

// ---------------------------------------------------------------------------
// prep: fp32 -> bf16 hi/lo split; 5 tensors batched via blockIdx.y
__global__ __launch_bounds__(256) void prep_all(
    const float* __restrict__ q, const float* __restrict__ k,
    const float* __restrict__ Wq, const float* __restrict__ Wk, const float* __restrict__ Wp,
    bf16* __restrict__ qh, bf16* __restrict__ ql,
    bf16* __restrict__ kh, bf16* __restrict__ kl,
    bf16* __restrict__ Wqh, bf16* __restrict__ Wql,
    bf16* __restrict__ Wkh, bf16* __restrict__ Wkl,
    bf16* __restrict__ Wph, bf16* __restrict__ Wpl,
    int nqk, int nw)
{
    const int z = blockIdx.y;
    const float* s; bf16* h; bf16* l; int n;
    switch (z) {
        case 0:  s = q;  h = qh;  l = ql;  n = nqk; break;
        case 1:  s = k;  h = kh;  l = kl;  n = nqk; break;
        case 2:  s = Wq; h = Wqh; l = Wql; n = nw;  break;
        case 3:  s = Wk; h = Wkh; l = Wkl; n = nw;  break;
        default: s = Wp; h = Wph; l = Wpl; n = nw;  break;
    }
    const int i = (blockIdx.x * 256 + threadIdx.x) * 4;
    if (i >= n) return;
    f32x4 v = *(const f32x4*)(s + i);
    bf16x4 hv, lv;
#pragma unroll
    for (int c = 0; c < 4; c++) {
        float x = v[c];
        bf16 hh = (bf16)x;
        hv[c] = hh;
        lv[c] = (bf16)(x - (float)hh);
    }
    *(bf16x4*)(h + i) = hv;
    *(bf16x4*)(l + i) = lv;
}

// ---------------------------------------------------------------------------
// reduce over NS partial slices. MODE 0: sum->bf16. MODE 1: sum+bias->f32.
template<int NS, int MODE>
__global__ __launch_bounds__(256) void reduce_k(
    const float* __restrict__ P, const float* __restrict__ bias,
    float* __restrict__ of, bf16* __restrict__ oh, int n, int Nld)
{
    const int i = (blockIdx.x * 256 + threadIdx.x) * 4;
    if (i >= n) return;
    f32x4 v = *(const f32x4*)(P + i);
#pragma unroll
    for (int s = 1; s < NS; s++)
        v += *(const f32x4*)(P + (size_t)s * n + i);
    if (MODE == 1)
        v += *(const f32x4*)(bias + (i & (Nld - 1)));
    if (MODE == 0) {
        bf16x4 o;
#pragma unroll
        for (int c = 0; c < 4; c++) o[c] = (bf16)v[c];
        *(bf16x4*)(oh + i) = o;
    } else {
        *(f32x4*)(of + i) = v;
    }
}

// ---------------------------------------------------------------------------
// Plain bf16 gemm_bt (32x32x16 core, swizzled LDS): C = A[M,K] B[N,K]^T.
// NSPLIT>0: blockIdx.z = kz -> fp32 partial slice kz.
template<int NSPLIT, int HAS_BIAS, int OUT_BF16>
__global__ __launch_bounds__(256) void gemm_bt(
    const bf16* __restrict__ A, const bf16* __restrict__ B,
    const float* __restrict__ bias,
    float* __restrict__ Cf, bf16* __restrict__ Cb,
    int M, int N, int Ksub, int lda, int ldb)
{
    __shared__ bf16 sA[BM * BK];
    __shared__ bf16 sB[BN * BK];
    const int t    = threadIdx.x;
    const int wave = t >> 6;
    const int lane = t & 63;
    const int l31  = lane & 31;
    const int lhi  = lane >> 5;
    const int wm   = wave >> 1;
    const int wn   = wave & 1;
    const int bm   = blockIdx.y * BM;
    const int bn   = blockIdx.x * BN;
    const int srow = t >> 2;
    const int gseg = (t & 3) ^ ((srow >> 1) & 3) ^ ((srow >> 3) & 3);
    const int rsw  = ((l31 >> 1) & 3) ^ ((l31 >> 3) & 3);
    const int kz   = (NSPLIT > 0) ? (int)blockIdx.z : 0;

    A += (size_t)kz * Ksub;
    B += (size_t)kz * Ksub;
    if (NSPLIT > 0) Cf += (size_t)kz * M * N;

    const bf16* ga = A + (size_t)(bm + srow) * lda + gseg * 8;
    const bf16* gb = B + (size_t)(bn + srow) * ldb + gseg * 8;
    char* lA = (char*)sA + wave * 1024;
    char* lB = (char*)sB + wave * 1024;

    f32x16 acc[2][2] = {};

    for (int k0 = 0; k0 < Ksub; k0 += BK) {
        __syncthreads();
        gld_lds16(ga + k0,                      lA);
        gld_lds16(ga + (size_t)64 * lda + k0,   lA + 4096);
        gld_lds16(gb + k0,                      lB);
        gld_lds16(gb + (size_t)64 * ldb + k0,   lB + 4096);
        __syncthreads();
        bf16x8 af[2][2], bfr[2][2];
#pragma unroll
        for (int mi = 0; mi < 2; mi++)
#pragma unroll
            for (int kh = 0; kh < 2; kh++)
                af[mi][kh] = *(const bf16x8*)
                    &sA[(wm * 64 + mi * 32 + l31) * BK + ((kh * 2 + lhi) ^ rsw) * 8];
#pragma unroll
        for (int nj = 0; nj < 2; nj++)
#pragma unroll
            for (int kh = 0; kh < 2; kh++)
                bfr[nj][kh] = *(const bf16x8*)
                    &sB[(wn * 64 + nj * 32 + l31) * BK + ((kh * 2 + lhi) ^ rsw) * 8];
#pragma unroll
        for (int kh = 0; kh < 2; kh++)
#pragma unroll
            for (int mi = 0; mi < 2; mi++)
#pragma unroll
                for (int nj = 0; nj < 2; nj++)
                    acc[mi][nj] = __builtin_amdgcn_mfma_f32_32x32x16_bf16(
                        af[mi][kh], bfr[nj][kh], acc[mi][nj], 0, 0, 0);
    }

#pragma unroll
    for (int mi = 0; mi < 2; mi++)
#pragma unroll
        for (int nj = 0; nj < 2; nj++) {
            const int cg = bn + wn * 64 + nj * 32 + l31;
            const float bv = HAS_BIAS ? bias[cg] : 0.0f;
#pragma unroll
            for (int r = 0; r < 16; r++) {
                const int rg = bm + wm * 64 + mi * 32 + (r & 3) + 8 * (r >> 2) + 4 * lhi;
                const float v = acc[mi][nj][r] + bv;
                const size_t idx = (size_t)rg * N + cg;
                if (NSPLIT > 0)    Cf[idx] = v;
                else if (OUT_BF16) Cb[idx] = (bf16)v;
                else               Cf[idx] = v;
            }
        }
}

// ---------------------------------------------------------------------------
// Split-precision gemm_bt (32x32x16, 2x2 wave tile; AlBh + AhBl + AhBh).
// Projections: BATCH via blockIdx.z, direct bias + hi/lo epilogue.
template<int BATCH, int HAS_BIAS, int HILO>
__global__ __launch_bounds__(256) void gemm_bt_split(
    const bf16* __restrict__ Ah0, const bf16* __restrict__ Al0,
    const bf16* __restrict__ Bh0, const bf16* __restrict__ Bl0,
    const float* __restrict__ bias0, bf16* __restrict__ Ch0, bf16* __restrict__ Cl0,
    const bf16* __restrict__ Ah1, const bf16* __restrict__ Al1,
    const bf16* __restrict__ Bh1, const bf16* __restrict__ Bl1,
    const float* __restrict__ bias1, bf16* __restrict__ Ch1, bf16* __restrict__ Cl1,
    float* __restrict__ Cf,
    int M, int N, int K)
{
    __shared__ bf16 sAh[BM * BK], sAl[BM * BK], sBh[BN * BK], sBl[BN * BK];
    const int t    = threadIdx.x;
    const int wave = t >> 6;
    const int lane = t & 63;
    const int l31  = lane & 31;
    const int lhi  = lane >> 5;
    const int wm   = wave >> 1;
    const int wn   = wave & 1;
    const int bm   = blockIdx.y * BM;
    const int bn   = blockIdx.x * BN;
    const int srow = t >> 2;
    const int gseg = (t & 3) ^ ((srow >> 1) & 3) ^ ((srow >> 3) & 3);
    const int rsw  = ((l31 >> 1) & 3) ^ ((l31 >> 3) & 3);

    const int mt = BATCH ? (int)blockIdx.z : 0;

    const bf16* Ah = (BATCH && mt) ? Ah1 : Ah0;
    const bf16* Al = (BATCH && mt) ? Al1 : Al0;
    const bf16* Bh = (BATCH && mt) ? Bh1 : Bh0;
    const bf16* Bl = (BATCH && mt) ? Bl1 : Bl0;
    const float* bias = (BATCH && mt) ? bias1 : bias0;
    bf16* Ch = (BATCH && mt) ? Ch1 : Ch0;
    bf16* Cl = (BATCH && mt) ? Cl1 : Cl0;

    const size_t offA = (size_t)(bm + srow) * K + gseg * 8;
    const size_t offB = (size_t)(bn + srow) * K + gseg * 8;
    char* lAh = (char*)sAh + wave * 1024;
    char* lAl = (char*)sAl + wave * 1024;
    char* lBh = (char*)sBh + wave * 1024;
    char* lBl = (char*)sBl + wave * 1024;

    f32x16 acc[2][2] = {};

    for (int k0 = 0; k0 < K; k0 += BK) {
        __syncthreads();
        gld_lds16(Ah + offA + k0,                  lAh);
        gld_lds16(Ah + offA + (size_t)64 * K + k0, lAh + 4096);
        gld_lds16(Al + offA + k0,                  lAl);
        gld_lds16(Al + offA + (size_t)64 * K + k0, lAl + 4096);
        gld_lds16(Bh + offB + k0,                  lBh);
        gld_lds16(Bh + offB + (size_t)64 * K + k0, lBh + 4096);
        gld_lds16(Bl + offB + k0,                  lBl);
        gld_lds16(Bl + offB + (size_t)64 * K + k0, lBl + 4096);
        __syncthreads();
#pragma unroll
        for (int kh = 0; kh < 2; kh++) {
            const int ksw = ((kh * 2 + lhi) ^ rsw) * 8;
            bf16x8 ah[2], al[2], bh2[2], bl2[2];
#pragma unroll
            for (int mi = 0; mi < 2; mi++) {
                const int ro = (wm * 64 + mi * 32 + l31) * BK + ksw;
                ah[mi] = *(const bf16x8*)&sAh[ro];
                al[mi] = *(const bf16x8*)&sAl[ro];
            }
#pragma unroll
            for (int nj = 0; nj < 2; nj++) {
                const int ro = (wn * 64 + nj * 32 + l31) * BK + ksw;
                bh2[nj] = *(const bf16x8*)&sBh[ro];
                bl2[nj] = *(const bf16x8*)&sBl[ro];
            }
#pragma unroll
            for (int mi = 0; mi < 2; mi++)
#pragma unroll
                for (int nj = 0; nj < 2; nj++) {
                    acc[mi][nj] = __builtin_amdgcn_mfma_f32_32x32x16_bf16(al[mi], bh2[nj], acc[mi][nj], 0, 0, 0);
                    acc[mi][nj] = __builtin_amdgcn_mfma_f32_32x32x16_bf16(ah[mi], bl2[nj], acc[mi][nj], 0, 0, 0);
                    acc[mi][nj] = __builtin_amdgcn_mfma_f32_32x32x16_bf16(ah[mi], bh2[nj], acc[mi][nj], 0, 0, 0);
                }
        }
    }

#pragma unroll
    for (int mi = 0; mi < 2; mi++)
#pragma unroll
        for (int nj = 0; nj < 2; nj++) {
            const int cg = bn + wn * 64 + nj * 32 + l31;
            const float bv = HAS_BIAS ? bias[cg] : 0.0f;
#pragma unroll
            for (int r = 0; r < 16; r++) {
                const int rg = bm + wm * 64 + mi * 32 + (r & 3) + 8 * (r >> 2) + 4 * lhi;
                const float v = acc[mi][nj][r] + bv;
                const size_t idx = (size_t)rg * N + cg;
                if (HILO) {
                    const bf16 hh = (bf16)v;
                    Ch[idx] = hh;
                    Cl[idx] = (bf16)(v - (float)hh);
                } else {
                    Cf[idx] = v;
                }
            }
        }
}

// ---------------------------------------------------------------------------
// R13 score GEMM: logits = qx kx^T (split precision), 256x256 tile,
// 512 threads = 8 waves (2M x 4N, per-wave 128x64 -> acc[4][2]).
// BK=16; FOUR 32KB LDS buffers (128KB total); prefetch distance 3;
// ONE s_barrier per K-chunk; constant vmcnt(8) (counted, never 0 in main
// loop); setprio(1) around the 24-MFMA burst. Per K-chunk per wave:
// 4 gld_lds16 (stage chunk t+3) + 12 ds_read_b128 + 24 MFMA.
// K-chunk order and AlBh->AhBl->AhBh trio order identical to R12 ->
// bit-identical accumulation. No LDS swizzle (R12 proved 4 conflicts per
// b128 is structural and swizzle-invariant for this granularity).
// After the score epilogue each block computes one 128x128 tile of
// kxpT = Wp kx^T (unchanged from R12).
__global__ __launch_bounds__(512, 2) void gemm_score256(
    const bf16* __restrict__ Ah, const bf16* __restrict__ Al,
    const bf16* __restrict__ Bh, const bf16* __restrict__ Bl,
    float* __restrict__ Cf,
    const bf16* __restrict__ Wp, const bf16* __restrict__ Kx,
    bf16* __restrict__ kxpT)
{
    __shared__ bf16 smem[65536];          // 128 KB = 4 bufs x 32 KB
    const int t    = threadIdx.x;
    const int wave = t >> 6;              // 0..7
    const int lane = t & 63;
    const int l31  = lane & 31;
    const int lhi  = lane >> 5;
    const int wm   = wave >> 2;           // 0..1 (M)
    const int wn   = wave & 3;            // 0..3 (N)
    const int bm   = (blockIdx.x >> 4) * 256;
    const int bn   = (blockIdx.x & 15) * 256;
    const int K    = EMB;

    // ---- staging map (BK=16): wave stages 32 rows; lane -> (row, seg)
    //   row = wave*32 + (lane>>1), seg = lane&1 (8 bf16 = 16B)
    //   LDS dest = waveBase + lane*16  ->  row-major, 32B rows, linear.
    const int strow = wave * 32 + (lane >> 1);
    const int stcol = (lane & 1) * 8;
    const bf16* gAh = Ah + (size_t)(bm + strow) * K + stcol;
    const bf16* gAl = Al + (size_t)(bm + strow) * K + stcol;
    const bf16* gBh = Bh + (size_t)(bn + strow) * K + stcol;
    const bf16* gBl = Bl + (size_t)(bn + strow) * K + stcol;

    // buf layout (bf16 elems): A_h @0, A_l @4096, B_h @8192, B_l @12288
    // buf b at elem b*16384 (byte b*32768).
    auto stage = [&](int sbB, int tt) {
        char* L = (char*)smem + sbB + wave * 1024;
        const int ko = tt * 16;
        gld_lds16(gAh + ko, L);
        gld_lds16(gAl + ko, L + 8192);
        gld_lds16(gBh + ko, L + 16384);
        gld_lds16(gBl + ko, L + 24576);
    };

    f32x16 acc[4][2] = {};

    // read offsets (elems within buf)
    const int aoff = (wm * 128 + l31) * 16 + lhi * 8;        // + mi*512
    const int boff = 8192 + (wn * 64 + l31) * 16 + lhi * 8;  // + nj*512

    auto tile_body = [&](int cbE, int sbB, int stt, bool do_stage) {
        __builtin_amdgcn_s_barrier();
        if (do_stage) stage(sbB, stt);
        bf16x8 a_h[4], a_l[4], b_h[2], b_l[2];
#pragma unroll
        for (int mi = 0; mi < 4; mi++) {
            a_h[mi] = *(const bf16x8*)&smem[cbE + aoff + mi * 512];
            a_l[mi] = *(const bf16x8*)&smem[cbE + 4096 + aoff + mi * 512];
        }
#pragma unroll
        for (int nj = 0; nj < 2; nj++) {
            b_h[nj] = *(const bf16x8*)&smem[cbE + boff + nj * 512];
            b_l[nj] = *(const bf16x8*)&smem[cbE + 4096 + boff + nj * 512];
        }
        asm volatile("s_waitcnt lgkmcnt(0)" ::: "memory");
        __builtin_amdgcn_sched_barrier(0);
        __builtin_amdgcn_s_setprio(1);
#pragma unroll
        for (int mi = 0; mi < 4; mi++)
#pragma unroll
            for (int nj = 0; nj < 2; nj++) {
                acc[mi][nj] = __builtin_amdgcn_mfma_f32_32x32x16_bf16(a_l[mi], b_h[nj], acc[mi][nj], 0, 0, 0);
                acc[mi][nj] = __builtin_amdgcn_mfma_f32_32x32x16_bf16(a_h[mi], b_l[nj], acc[mi][nj], 0, 0, 0);
                acc[mi][nj] = __builtin_amdgcn_mfma_f32_32x32x16_bf16(a_h[mi], b_h[nj], acc[mi][nj], 0, 0, 0);
            }
        __builtin_amdgcn_s_setprio(0);
    };

#define VW8 asm volatile("s_waitcnt vmcnt(8)" ::: "memory")
#define VW4 asm volatile("s_waitcnt vmcnt(4)" ::: "memory")
#define VW0 asm volatile("s_waitcnt vmcnt(0)" ::: "memory")

    // prologue: stage chunks 0,1,2 into bufs 0,1,2
    stage(0, 0); stage(32768, 1); stage(65536, 2);

    // main loop: chunks 0..59 (15 x 4, buffer index compile-time constant)
    for (int tb = 0; tb < 60; tb += 4) {
        VW8; tile_body(    0,  98304, tb + 3, true);   // buf0, stage->buf3
        VW8; tile_body(16384,      0, tb + 4, true);   // buf1, stage->buf0
        VW8; tile_body(32768,  32768, tb + 5, true);   // buf2, stage->buf1
        VW8; tile_body(49152,  65536, tb + 6, true);   // buf3, stage->buf2
    }
    // tail: chunks 60..63
    VW8; tile_body(    0,  98304, 63, true);           // buf0, stage 63->buf3
    VW8; tile_body(16384,      0,  0, false);          // buf1
    VW4; tile_body(32768,      0,  0, false);          // buf2
    VW0; tile_body(49152,      0,  0, false);          // buf3

#undef VW8
#undef VW4
#undef VW0

    // ---- score C-write (fp32 logits)
#pragma unroll
    for (int mi = 0; mi < 4; mi++)
#pragma unroll
        for (int nj = 0; nj < 2; nj++) {
            const int cg = bn + wn * 64 + nj * 32 + l31;
#pragma unroll
            for (int r = 0; r < 16; r++) {
                const int rg = bm + wm * 128 + mi * 32 + (r & 3) + 8 * (r >> 2) + 4 * lhi;
                Cf[(size_t)rg * NKK + cg] = acc[mi][nj][r];
            }
        }

    // ---- kxpT tile: C[m,n] = sum_k Wp[m,k] Kx[n,k]; 128x128 per block.
    // 8 waves (4M x 2N, per-wave 32x64). Unchanged from R12 (bit-exact).
    {
        const int srow = t >> 2;
        const int gseg = (t & 3) ^ ((srow >> 1) & 3) ^ ((srow >> 3) & 3);
        const int rsw  = ((l31 >> 1) & 3) ^ ((l31 >> 3) & 3);
        const int km  = (blockIdx.x >> 5) * 128;   // over EMB/128 = 8
        const int kn2 = (blockIdx.x & 31) * 128;   // over NKK/128 = 32
        const int wm4 = wave >> 1;
        const int wn2 = wave & 1;
        const int NT2 = K / BK;                    // 32
        const bf16* gW = Wp + (size_t)(km  + srow) * K + gseg * 8;
        const bf16* gX = Kx + (size_t)(kn2 + srow) * K + gseg * 8;
        // buffer b (bytes): W @ b*16384+0, X @ +8192
        auto stageK = [&](int buf, int k0) {
            char* L = (char*)smem + buf * 16384 + wave * 1024;
            gld_lds16(gW + k0, L);
            gld_lds16(gX + k0, L + 8192);
        };
        f32x16 ac2[2] = {};
        stageK(0, 0);
        for (int it = 0; it < NT2; ++it) {
            const int cur = it & 1;
            const int cb  = cur * 8192;    // elem base
            if (it < NT2 - 1) {
                stageK(cur ^ 1, (it + 1) * BK);
                asm volatile("s_waitcnt vmcnt(2)" ::: "memory");
            } else {
                asm volatile("s_waitcnt vmcnt(0)" ::: "memory");
            }
            __builtin_amdgcn_s_barrier();
#pragma unroll
            for (int kh = 0; kh < 2; kh++) {
                const int ksw = ((kh * 2 + lhi) ^ rsw) * 8;
                bf16x8 av  = *(const bf16x8*)&smem[cb + (wm4 * 32 + l31) * BK + ksw];
                bf16x8 bv0 = *(const bf16x8*)&smem[cb + 4096 + (wn2 * 64 + l31) * BK + ksw];
                bf16x8 bv1 = *(const bf16x8*)&smem[cb + 4096 + (wn2 * 64 + 32 + l31) * BK + ksw];
                ac2[0] = __builtin_amdgcn_mfma_f32_32x32x16_bf16(av, bv0, ac2[0], 0, 0, 0);
                ac2[1] = __builtin_amdgcn_mfma_f32_32x32x16_bf16(av, bv1, ac2[1], 0, 0, 0);
            }
            asm volatile("s_waitcnt lgkmcnt(0)" ::: "memory");
            __builtin_amdgcn_s_barrier();
        }
#pragma unroll
        for (int nj = 0; nj < 2; nj++) {
            const int cg = kn2 + wn2 * 64 + nj * 32 + l31;
#pragma unroll
            for (int r = 0; r < 16; r++) {
                const int rg = km + wm4 * 32 + (r & 3) + 8 * (r >> 2) + 4 * lhi;
                kxpT[(size_t)rg * NKK + cg] = (bf16)ac2[nj][r];
            }
        }
    }
}

// ---------------------------------------------------------------------------
__device__ __forceinline__ float wred_max(float v) {
#pragma unroll
    for (int off = 32; off > 0; off >>= 1) v = fmaxf(v, __shfl_xor(v, off));
    return v;
}
__device__ __forceinline__ float wred_sum(float v) {
#pragma unroll
    for (int off = 32; off > 0; off >>= 1) v += __shfl_xor(v, off);
    return v;
}

// Fused double softmax, vectorized (16 contiguous cols/thread).
__global__ __launch_bounds__(256) void softmax2_kernel(
    float* __restrict__ score, const int* __restrict__ mask,
    const float* __restrict__ wei, bf16* __restrict__ scoreb)
{
    __shared__ float sred[4];
    const int row = blockIdx.x;
    const int t   = threadIdx.x;
    const size_t base = (size_t)row * NKK + (size_t)t * 16;
    const int wv = t >> 6, ln = t & 63;

    float l[16], w[16];
    unsigned mb = 0;
#pragma unroll
    for (int c = 0; c < 4; c++) {
        *(f32x4*)(l + 4 * c) = *(const f32x4*)(score + base + 4 * c);
        *(f32x4*)(w + 4 * c) = *(const f32x4*)(wei + base + 4 * c);
        i32x4 mv = *(const i32x4*)(mask + base + 4 * c);
#pragma unroll
        for (int j = 0; j < 4; j++) if (mv[j] != 0) mb |= 1u << (4 * c + j);
    }

    // pass 1
    float mx = -__builtin_inff();
#pragma unroll
    for (int s = 0; s < 16; s++) if (mb & (1u << s)) mx = fmaxf(mx, l[s]);
    mx = wred_max(mx);
    if (ln == 0) sred[wv] = mx;
    __syncthreads();
    mx = fmaxf(fmaxf(sred[0], sred[1]), fmaxf(sred[2], sred[3]));
    __syncthreads();
    float sum = 0.f;
#pragma unroll
    for (int s = 0; s < 16; s++) {
        const float e = (mb & (1u << s)) ? __expf(l[s] - mx) : 0.f;
        l[s] = e; sum += e;
    }
    sum = wred_sum(sum);
    if (ln == 0) sred[wv] = sum;
    __syncthreads();
    sum = sred[0] + sred[1] + sred[2] + sred[3];
    __syncthreads();
    const float inv1 = 1.0f / sum;

#pragma unroll
    for (int s = 0; s < 16; s++) l[s] = l[s] * inv1 * w[s];

    // pass 2
    float mx2 = -__builtin_inff();
#pragma unroll
    for (int s = 0; s < 16; s++) if (mb & (1u << s)) mx2 = fmaxf(mx2, l[s]);
    mx2 = wred_max(mx2);
    if (ln == 0) sred[wv] = mx2;
    __syncthreads();
    mx2 = fmaxf(fmaxf(sred[0], sred[1]), fmaxf(sred[2], sred[3]));
    __syncthreads();
    float sum2 = 0.f;
#pragma unroll
    for (int s = 0; s < 16; s++) {
        const float e = (mb & (1u << s)) ? __expf(l[s] - mx2) : 0.f;
        l[s] = e; sum2 += e;
    }
    sum2 = wred_sum(sum2);
    if (ln == 0) sred[wv] = sum2;
    __syncthreads();
    sum2 = sred[0] + sred[1] + sred[2] + sred[3];
    const float inv2 = 1.0f / sum2;

#pragma unroll
    for (int c = 0; c < 4; c++) {
        f32x4 pv;
#pragma unroll
        for (int j = 0; j < 4; j++) pv[j] = l[4 * c + j] * inv2;
        __builtin_nontemporal_store(pv, (f32x4*)(score + base + 4 * c));
#pragma unroll
        for (int j = 0; j < 4; j++) l[4 * c + j] = pv[j];
    }
    bf16x8 b0, b1;
#pragma unroll
    for (int j = 0; j < 8; j++) { b0[j] = (bf16)l[j]; b1[j] = (bf16)l[8 + j]; }
    *(bf16x8*)(scoreb + base)     = b0;
    *(bf16x8*)(scoreb + base + 8) = b1;
}

// ---------------------------------------------------------------------------
extern "C" void kernel_launch(void* const* d_in, const int* in_sizes, int n_in,
                              void* d_out, int out_size, void* d_ws, size_t ws_size,
                              hipStream_t stream)
{
    (void)in_sizes; (void)n_in; (void)out_size;
    const float* q    = (const float*)d_in[0];
    const float* k    = (const float*)d_in[1];
    const int*   mask = (const int*)  d_in[2];
    const float* wei  = (const float*)d_in[3];
    const float* Wq   = (const float*)d_in[4];
    const float* bq   = (const float*)d_in[5];
    const float* Wk   = (const float*)d_in[6];
    const float* bk   = (const float*)d_in[7];
    const float* Wp   = (const float*)d_in[8];
    const float* bp   = (const float*)d_in[9];

    float* out   = (float*)d_out;
    float* score = (float*)d_out + (size_t)NQ * EMB;

    char* ws = (char*)d_ws;
    size_t off = 0;
    auto alloc = [&](size_t bytes) -> char* {
        char* p = ws + off; off += (bytes + 255) & ~(size_t)255; return p;
    };
    const size_t n_qk = (size_t)NQ * EMB;
    const size_t n_w  = (size_t)EMB * EMB;
    const size_t n_sc = (size_t)NQ * NKK;

    bf16* qh   = (bf16*)alloc(n_qk * 2);
    bf16* ql   = (bf16*)alloc(n_qk * 2);
    bf16* kh   = (bf16*)alloc(n_qk * 2);
    bf16* kl   = (bf16*)alloc(n_qk * 2);
    bf16* qxh  = (bf16*)alloc(n_qk * 2);
    bf16* qxl  = (bf16*)alloc(n_qk * 2);
    bf16* kxh  = (bf16*)alloc(n_qk * 2);
    bf16* kxl  = (bf16*)alloc(n_qk * 2);
    bf16* Wqh  = (bf16*)alloc(n_w * 2);
    bf16* Wql  = (bf16*)alloc(n_w * 2);
    bf16* Wkh  = (bf16*)alloc(n_w * 2);
    bf16* Wkl  = (bf16*)alloc(n_w * 2);
    bf16* Wpb  = (bf16*)alloc(n_w * 2);
    bf16* Wpl  = (bf16*)alloc(n_w * 2);
    bf16* kxpTb = (bf16*)alloc(n_qk * 2);   // kxpT = Wp kx^T  [1024 x 4096]
    bf16* scoreb = (bf16*)alloc(n_sc * 2);
    const size_t base_off = off;
    float* P = (float*)alloc(2 * n_qk * 4); // 33.5 MB partials (split-K=2)
    const bool ws_ok = (off <= ws_size);
    if (base_off > ws_size) return;

    const int MN = (int)n_qk;

    // 1) prep: all 5 hi/lo splits in one launch
    prep_all<<<dim3(n_qk / 1024, 5), 256, 0, stream>>>(
        q, k, Wq, Wk, Wp,
        qh, ql, kh, kl, Wqh, Wql, Wkh, Wkl, Wpb, Wpl,
        (int)n_qk, (int)n_w);

    // 2) projections: batched z=2, direct bias + hi/lo epilogue
    gemm_bt_split<1, 1, 1><<<dim3(EMB / BN, NQ / BM, 2), 256, 0, stream>>>(
        qh, ql, Wqh, Wql, bq, qxh, qxl,
        kh, kl, Wkh, Wkl, bk, kxh, kxl,
        nullptr, NQ, EMB, EMB);

    // 3) score logits (256 blocks, 256x256 tile, BK=16 quad-buffered counted
    //    vmcnt) with one 128x128 kxpT = Wp kx^T tile per block appended
    gemm_score256<<<dim3(256), 512, 0, stream>>>(
        qxh, qxl, kxh, kxl, score, Wpb, kxh, kxpTb);

    // 4) fused double softmax (vectorized, mask int4, p2 nontemporal)
    softmax2_kernel<<<dim3(NQ), 256, 0, stream>>>(score, mask, wei, scoreb);

    // 5) out = p2 kxp + bp  (split-K=2 over K=4096)
    if (ws_ok) {
        gemm_bt<2, 0, 0><<<dim3(EMB / BN, NQ / BM, 2), 256, 0, stream>>>(
            scoreb, kxpTb, nullptr, P, nullptr, NQ, EMB, NKK / 2, NKK, NKK);
        reduce_k<2, 1><<<dim3(MN / 1024), 256, 0, stream>>>(
            P, bp, out, nullptr, MN, EMB);
    } else {
        gemm_bt<0, 1, 0><<<dim3(EMB / BN, NQ / BM), 256, 0, stream>>>(
            scoreb, kxpTb, bp, out, nullptr, NQ, EMB, NKK, NKK, NKK);
    }
}